// Round 3
// baseline (238.640 us; speedup 1.0000x reference)
//
#include <hip/hip_runtime.h>

// LIF scan: u = 0.5*u + x_t; o = (u > 1); u = 0 where spiked.
// x: [B=32, T=128, N=8192] fp32; out same, values in {0,1}.
//
// R1/R2 lesson: BW pinned at 2.4 TB/s in BOTH configs -> ~1 outstanding
// vmem op per wave (latency model: 0.9 MB in flight / waves). Fix = MLP:
//  - float4 (1KB per wave-op)
//  - T chunked 4x (warm-up 32 steps; 0.5^32 decay + spike-sync => exact
//    in practice; chunk 0 exact by construction)
//  - explicit 8-deep load batches so 8 loads are in flight per wave
// Grid: 32*2048*4 threads = 1024 blocks = 4/CU.

constexpr int B  = 32;
constexpr int T  = 128;
constexpr int N  = 8192;
constexpr int N4 = N / 4;      // 2048
constexpr int C  = 4;          // T-chunks
constexpr int L  = 32;         // outputs per chunk
constexpr int W  = 32;         // warm-up steps

__device__ __forceinline__ void warm4(float4& u, const float4 xt) {
    u.x = 0.5f * u.x + xt.x;  u.x = (u.x > 1.0f) ? 0.0f : u.x;
    u.y = 0.5f * u.y + xt.y;  u.y = (u.y > 1.0f) ? 0.0f : u.y;
    u.z = 0.5f * u.z + xt.z;  u.z = (u.z > 1.0f) ? 0.0f : u.z;
    u.w = 0.5f * u.w + xt.w;  u.w = (u.w > 1.0f) ? 0.0f : u.w;
}

__device__ __forceinline__ void step4(float4& u, const float4 xt, float4& o) {
    u.x = 0.5f * u.x + xt.x;  o.x = (u.x > 1.0f) ? 1.0f : 0.0f;  u.x = (u.x > 1.0f) ? 0.0f : u.x;
    u.y = 0.5f * u.y + xt.y;  o.y = (u.y > 1.0f) ? 1.0f : 0.0f;  u.y = (u.y > 1.0f) ? 0.0f : u.y;
    u.z = 0.5f * u.z + xt.z;  o.z = (u.z > 1.0f) ? 1.0f : 0.0f;  u.z = (u.z > 1.0f) ? 0.0f : u.z;
    u.w = 0.5f * u.w + xt.w;  o.w = (u.w > 1.0f) ? 1.0f : 0.0f;  u.w = (u.w > 1.0f) ? 0.0f : u.w;
}

__global__ __launch_bounds__(256) void lif_kernel(const float4* __restrict__ x,
                                                  float4* __restrict__ out) {
    int idx = blockIdx.x * blockDim.x + threadIdx.x;   // [0, B*N4*C)
    int c   = idx >> 16;          // / (B*N4) = /65536  -> chunk id (block-uniform)
    int rem = idx & 65535;
    int b   = rem >> 11;          // / N4
    int n   = rem & (N4 - 1);
    size_t base = (size_t)b * T * N4 + n;
    const float4* xp = x   + base;
    float4*       op = out + base;

    const int t0 = c * L;
    float4 u = make_float4(0.f, 0.f, 0.f, 0.f);

    // Warm-up: re-integrate [t0-W, t0) from u=0. Block-uniform branch.
    if (c > 0) {
        const int tw = t0 - W;
        #pragma unroll
        for (int blk = 0; blk < W / 8; ++blk) {
            float4 xs[8];
            #pragma unroll
            for (int j = 0; j < 8; ++j)
                xs[j] = xp[(size_t)(tw + blk * 8 + j) * N4];
            #pragma unroll
            for (int j = 0; j < 8; ++j)
                warm4(u, xs[j]);
        }
    }

    // Main: compute + store [t0, t0+L)
    #pragma unroll
    for (int blk = 0; blk < L / 8; ++blk) {
        float4 xs[8];
        #pragma unroll
        for (int j = 0; j < 8; ++j)
            xs[j] = xp[(size_t)(t0 + blk * 8 + j) * N4];
        float4 os[8];
        #pragma unroll
        for (int j = 0; j < 8; ++j)
            step4(u, xs[j], os[j]);
        #pragma unroll
        for (int j = 0; j < 8; ++j)
            op[(size_t)(t0 + blk * 8 + j) * N4] = os[j];
    }
}

extern "C" void kernel_launch(void* const* d_in, const int* in_sizes, int n_in,
                              void* d_out, int out_size, void* d_ws, size_t ws_size,
                              hipStream_t stream) {
    const float4* x  = (const float4*)d_in[0];
    float4*      out = (float4*)d_out;
    int total = B * N4 * C;                      // 262144 threads
    lif_kernel<<<total / 256, 256, 0, stream>>>(x, out);
}

// Round 4
// 232.187 us; speedup vs baseline: 1.0278x; 1.0278x over previous
//
#include <hip/hip_runtime.h>
#include <stdint.h>

// LIF scan: u = 0.5*u + x_t; o = (u > 1); u = 0 where spiked.
// x: [B=32, T=128, N=8192] fp32; out same, values in {0,1}. Bit-exact (no chunking).
//
// R1-R3 lesson: register-resident recurrence fed by global loads is hostage to
// compiler vmcnt scheduling (VGPR=32 proved the 8-deep batch never existed);
// BW pinned at 2.4-2.8 TB/s regardless of occupancy. Fix: decouple the stream
// from the chain. global_load_lds double-buffer staging (memcpy-shaped, zero
// VGPR pressure, fire-and-forget until barrier); recurrence reads LDS.
// Block = 256 n-columns x full T. 2 x 16KB buffers. 1024 blocks = 4/CU.

constexpr int B   = 32;
constexpr int T   = 128;
constexpr int N   = 8192;
constexpr int N4  = N / 4;       // 2048 float4 per (b,t) row
constexpr int TC  = 16;          // timesteps per staged chunk
constexpr int NC  = T / TC;      // 8 chunks
constexpr int NW4 = 64;          // float4 columns per block = 256 floats

__device__ __forceinline__ void async16(void* lds_dst, const void* g_src) {
    __builtin_amdgcn_global_load_lds(
        (const __attribute__((address_space(1))) void*)g_src,
        (__attribute__((address_space(3))) void*)lds_dst, 16, 0, 0);
}

__global__ __launch_bounds__(256) void lif_kernel(const float4* __restrict__ x,
                                                  float* __restrict__ out) {
    __shared__ float4 buf[2][TC][NW4];            // 2 x 16 KB

    const int tid   = threadIdx.x;
    const int wave  = tid >> 6;
    const int lane  = tid & 63;
    const int b     = blockIdx.x >> 5;            // 32 n-tiles per batch row
    const int ntile = blockIdx.x & 31;
    const size_t xbase4 = (size_t)b * T * N4 + (size_t)ntile * NW4;       // float4 units
    const size_t obase  = (size_t)b * T * N  + (size_t)ntile * (NW4 * 4) + tid;

    // stage chunk 0: 16 t-rows x 64 float4; each wave-load = 1 KB contiguous,
    // LDS dest = wave-uniform base + lane*16 (global_load_lds constraint).
    {
        const float4* g0 = x + xbase4;
        #pragma unroll
        for (int k = 0; k < TC / 4; ++k) {
            const int t_sub = k * 4 + wave;
            async16(&buf[0][t_sub][lane], g0 + (size_t)t_sub * N4 + lane);
        }
    }

    float u = 0.f;
    #pragma unroll
    for (int c = 0; c < NC; ++c) {
        __syncthreads();          // vmcnt(0) drain -> chunk c resident in LDS
        if (c + 1 < NC) {         // prefetch chunk c+1 into the other buffer;
            const float4* g = x + xbase4 + (size_t)(c + 1) * TC * N4;
            #pragma unroll
            for (int k = 0; k < TC / 4; ++k) {
                const int t_sub = k * 4 + wave;
                async16(&buf[(c + 1) & 1][t_sub][lane], g + (size_t)t_sub * N4 + lane);
            }
        }
        // recurrence: thread owns one n-column; lds read = 2-way bank alias (free)
        const float* lb = (const float*)buf[c & 1];
        float* op = out + obase + (size_t)c * TC * N;
        #pragma unroll
        for (int t = 0; t < TC; ++t) {
            const float xt = lb[t * 256 + tid];
            u = 0.5f * u + xt;
            const float o = (u > 1.0f) ? 1.0f : 0.0f;
            u = (u > 1.0f) ? 0.0f : u;
            op[(size_t)t * N] = o;   // 64 lanes x 4B consecutive = coalesced 256B
        }
    }
}

extern "C" void kernel_launch(void* const* d_in, const int* in_sizes, int n_in,
                              void* d_out, int out_size, void* d_ws, size_t ws_size,
                              hipStream_t stream) {
    const float* x  = (const float*)d_in[0];
    float*      out = (float*)d_out;
    const int nblocks = B * (N / (NW4 * 4));      // 32 * 32 = 1024
    lif_kernel<<<nblocks, 256, 0, stream>>>((const float4*)x, out);
}